// Round 10
// baseline (1026.104 us; speedup 1.0000x reference)
//
#include <hip/hip_runtime.h>
#include <cstdint>
#include <cstddef>

#define NN 100000
#define BN_EPS 1e-5f

// bucketed CSR build: 128 nodes per bucket
#define NB_SHIFT 7
#define NBUCK ((NN >> NB_SHIFT) + 1)   // 782
#define BSLOT 6400                     // pair slots per bucket (mean 4093, sigma 64)
#define T1_EPT 16
#define T1_TILE (256*T1_EPT)           // 4096 edges per pass-1 block

// sliced fp8 feature tables: slice stride in bytes (32 fp8 cols per slice)
#define SL_STRIDE ((size_t)(NN+1)*32)

typedef __attribute__((ext_vector_type(8))) short short8;
typedef __attribute__((ext_vector_type(4))) float f32x4;
typedef __attribute__((ext_vector_type(2))) float f32x2;

static __device__ __forceinline__ float bflo(unsigned u){ return __uint_as_float(u<<16); }
static __device__ __forceinline__ float bfhi(unsigned u){ return __uint_as_float(u & 0xFFFF0000u); }
static __device__ __forceinline__ unsigned short f2bf(float f){
  unsigned u = __float_as_uint(f);
  u += 0x7FFFu + ((u>>16)&1u);   // round-to-nearest-even
  return (unsigned short)(u>>16);
}
static __device__ __forceinline__ unsigned pk2(float a, float b){
  return (unsigned)f2bf(a) | ((unsigned)f2bf(b) << 16);
}

// ---------------- graph prep (bucketed, histogram-free CSR build) ----------------

// pass 1: partition edges into NBUCK fixed-capacity segments of packed
// (src | localdst<<20) words. src < 2^17, localdst = dst&127 in bits 20..26.
__global__ __launch_bounds__(256) void k_b1(const int* __restrict__ src,
    const int* __restrict__ dst, int* __restrict__ bcnt,
    int* __restrict__ epairs, int E){
  __shared__ int hist[NBUCK];
  int tid = threadIdx.x;
  for(int j=tid; j<NBUCK; j+=256) hist[j]=0;
  __syncthreads();
  int base = blockIdx.x*T1_TILE;
  int pk[T1_EPT], bk[T1_EPT], r[T1_EPT];
  #pragma unroll
  for(int i=0;i<T1_EPT;i++){
    int e = base + i*256 + tid;
    if(e<E){
      int s=src[e], d=dst[e];
      bk[i]=d>>NB_SHIFT;
      pk[i]= s | ((d&127)<<20);
      r[i]=atomicAdd(&hist[bk[i]], 1);
    }
  }
  __syncthreads();
  for(int j=tid; j<NBUCK; j+=256){
    int h = hist[j];
    if(h>0) hist[j] = atomicAdd(&bcnt[j*16], h);   // replace count with segment base
  }
  __syncthreads();
  #pragma unroll
  for(int i=0;i<T1_EPT;i++){
    int e = base + i*256 + tid;
    if(e<E) epairs[(size_t)bk[i]*BSLOT + hist[bk[i]] + r[i]] = pk[i];
  }
}

// pass 2a: per-bucket LDS degree histogram -> norm[], deg[], padded bucket total.
__global__ __launch_bounds__(256) void k_b2a(const int* __restrict__ epairs,
    const int* __restrict__ bcnt, float* __restrict__ norm, int* __restrict__ deg,
    int* __restrict__ ptot){
  __shared__ int h[128];
  int b = blockIdx.x, tid = threadIdx.x;
  if(tid<128) h[tid]=0;
  __syncthreads();
  int c = bcnt[b*16];
  const int* ep = epairs + (size_t)b*BSLOT;
  for(int j=tid; j<c; j+=256) atomicAdd(&h[ep[j]>>20], 1);
  __syncthreads();
  int n0 = b<<NB_SHIFT, nmax = min(128, NN-n0);
  if(tid<nmax){
    norm[n0+tid] = rsqrtf(fmaxf((float)h[tid], 1.0f));
    deg[n0+tid] = h[tid];
  }
  if(tid<64){
    int p0=(h[2*tid]+7)&~7, p1=(h[2*tid+1]+7)&~7;
    int s=p0+p1;
    #pragma unroll
    for(int off=1; off<64; off<<=1) s += __shfl_xor(s, off, 64);
    if(tid==0) ptot[b]=s;
  }
}

// scan over 782 bucket totals (tiny); also rp[NN] and norm[NN]=0.
__global__ __launch_bounds__(1024) void k_scanB(const int* __restrict__ ptot,
    int* __restrict__ bbase, int* __restrict__ rp, float* __restrict__ norm){
  __shared__ int sm[1024];
  int t = threadIdx.x;
  int v = (t<NBUCK)? ptot[t] : 0;
  sm[t]=v; __syncthreads();
  for(int off=1; off<1024; off<<=1){
    int u = (t>=off)? sm[t-off] : 0;
    __syncthreads();
    sm[t]+=u;
    __syncthreads();
  }
  if(t<NBUCK) bbase[t] = sm[t]-v;
  if(t==NBUCK-1){ bbase[NBUCK]=sm[t]; rp[NN]=sm[t]; }
  if(t==0) norm[NN]=0.f;
}

// pass 2b: load deg, wave shuffle-scan of padded counts -> rp, place edges via
// LDS atomics, write pad slots (NN).
__global__ __launch_bounds__(256) void k_b2b(const int* __restrict__ epairs,
    const int* __restrict__ bcnt, const int* __restrict__ bbase,
    const int* __restrict__ deg, int* __restrict__ rp, int* __restrict__ esrc){
  __shared__ int h[128];
  __shared__ int loc[129];
  int b = blockIdx.x, tid = threadIdx.x;
  int n0 = b<<NB_SHIFT, nmax = min(128, NN-n0);
  if(tid<128) h[tid] = (tid<nmax) ? deg[n0+tid] : 0;
  __syncthreads();
  if(tid<64){
    int p0=(h[2*tid]+7)&~7, p1=(h[2*tid+1]+7)&~7;
    int s=p0+p1;
    #pragma unroll
    for(int off=1; off<64; off<<=1){ int u=__shfl_up(s, off, 64); if(tid>=off) s+=u; }
    loc[2*tid]   = s-p0-p1;
    loc[2*tid+1] = s-p1;
    if(tid==63) loc[128]=s;
  }
  __syncthreads();
  int base = bbase[b];
  if(tid<nmax) rp[n0+tid] = base + loc[tid];
  if(tid<128) h[tid] = base + loc[tid];          // becomes fill pointer
  __syncthreads();
  int c = bcnt[b*16];
  const int* ep = epairs + (size_t)b*BSLOT;
  for(int j=tid; j<c; j+=256){
    int p = ep[j];
    int pos = atomicAdd(&h[p>>20], 1);
    esrc[pos] = p & 0xFFFFF;
  }
  __syncthreads();
  for(int i=tid; i<nmax; i+=256){
    int end = base + loc[i+1];
    for(int j=h[i]; j<end; j++) esrc[j]=NN;
  }
}

// ---------------- fused prep: zeropad + 3x wprep + scale_x(fp8, sliced) ----------------
// bid 0: zero pad rows. bids [1,129): W1 transp. [129,385): W2 transp.
// [385,449): W3 pack. [449,6699): Hx8 = fp8(x*norm), sliced layout.
#define PB_W1 1
#define PB_W2 129
#define PB_W3 385
#define PB_SX 449
#define PB_END (PB_SX + 6250)

__global__ __launch_bounds__(256) void k_prep(
    const float* __restrict__ W1, const float* __restrict__ W2, const float* __restrict__ W3,
    const float* __restrict__ x, const float* __restrict__ norm,
    unsigned short* __restrict__ Wt1, unsigned short* __restrict__ Wt2,
    unsigned short* __restrict__ Wt3, unsigned char* __restrict__ Hx8,
    unsigned short* __restrict__ X3p, unsigned short* __restrict__ Z){
  int bid = blockIdx.x, t = threadIdx.x;
  if(bid == 0){
    // Hx8 zero row NN across 4 slices (32B each)
    if(t<128) Hx8[(size_t)(t>>5)*SL_STRIDE + (size_t)NN*32 + (t&31)] = 0;
    if(t<40)  X3p[(size_t)NN*64 + t] = 0;
    Z[(size_t)NN*256 + t] = 0;
  }else if(bid < PB_W2){
    int i = (bid-PB_W1)*256 + t;          // < 128*256
    int k = i >> 8, n = i & 255;
    Wt1[(size_t)n*128 + k] = f2bf(W1[i]);
  }else if(bid < PB_W3){
    int i = (bid-PB_W2)*256 + t;          // < 256*256
    int k = i >> 8, n = i & 255;
    Wt2[(size_t)n*256 + k] = f2bf(W2[i]);
  }else if(bid < PB_SX){
    int i = (bid-PB_W3)*256 + t;          // < 64*256
    int n = i >> 8, k = i & 255;
    Wt3[i] = (n < 40) ? f2bf(W3[(size_t)k*40 + n]) : (unsigned short)0;
  }else{
    int i = (bid-PB_SX)*256 + t;          // < N*16 (8 elems each)
    float4 v0 = *(const float4*)(x + (size_t)i*8);
    float4 v1 = *(const float4*)(x + (size_t)i*8 + 4);
    int row = i >> 4, q = i & 15;         // q*8 = col offset in 128-col row
    float nn = norm[row];
    int p0 = __builtin_amdgcn_cvt_pk_fp8_f32(v0.x*nn, v0.y*nn, 0, false);
    p0     = __builtin_amdgcn_cvt_pk_fp8_f32(v0.z*nn, v0.w*nn, p0, true);
    int p1 = __builtin_amdgcn_cvt_pk_fp8_f32(v1.x*nn, v1.y*nn, 0, false);
    p1     = __builtin_amdgcn_cvt_pk_fp8_f32(v1.z*nn, v1.w*nn, p1, true);
    uint2 w; w.x = (unsigned)p0; w.y = (unsigned)p1;
    // sliced write: slice q>>2 (32-col slices), within-slice byte (q&3)*8
    *(uint2*)(Hx8 + (size_t)(q>>2)*SL_STRIDE + (size_t)row*32 + (q&3)*8) = w;
  }
}

// ---------------- BN+ReLU pass -> fp8 e4m3, sliced layout ----------------

// H8s = fp8(relu(bn(Z1)) * norm[row]), 8 slice arrays of 32 cols each.
// Row NN -> 0 via norm[NN]=0 (pad-edge killer).
__global__ __launch_bounds__(256) void k_bnrelu8(const unsigned short* __restrict__ Z,
    const float* __restrict__ sums, const float* __restrict__ gamma,
    const float* __restrict__ beta, const float* __restrict__ norm,
    unsigned char* __restrict__ H8, int total4){
  __shared__ float s_sc[256], s_sh[256];
  int t = threadIdx.x;
  {
    float mean = sums[t]*(1.0f/NN);
    float var  = sums[256+t]*(1.0f/NN) - mean*mean;
    float sc = gamma[t]*rsqrtf(var + BN_EPS);
    s_sc[t] = sc;
    s_sh[t] = beta[t] - mean*sc;
  }
  __syncthreads();
  int i = blockIdx.x*blockDim.x + t;
  if(i<total4){
    int q = i & 31;                       // q*8 = col offset in 256-col row
    int row = i >> 5;
    int c8 = q * 8;
    float nn = norm[row];
    uint4 v = *(const uint4*)(Z + (size_t)i*8);
    float4 sc0 = *(const float4*)(s_sc + c8);
    float4 sc1 = *(const float4*)(s_sc + c8 + 4);
    float4 sh0 = *(const float4*)(s_sh + c8);
    float4 sh1 = *(const float4*)(s_sh + c8 + 4);
    float f0 = fmaxf(bflo(v.x)*sc0.x+sh0.x,0.f)*nn;
    float f1 = fmaxf(bfhi(v.x)*sc0.y+sh0.y,0.f)*nn;
    float f2 = fmaxf(bflo(v.y)*sc0.z+sh0.z,0.f)*nn;
    float f3 = fmaxf(bfhi(v.y)*sc0.w+sh0.w,0.f)*nn;
    float f4 = fmaxf(bflo(v.z)*sc1.x+sh1.x,0.f)*nn;
    float f5 = fmaxf(bfhi(v.z)*sc1.y+sh1.y,0.f)*nn;
    float f6 = fmaxf(bflo(v.w)*sc1.z+sh1.z,0.f)*nn;
    float f7 = fmaxf(bfhi(v.w)*sc1.w+sh1.w,0.f)*nn;
    int p0 = __builtin_amdgcn_cvt_pk_fp8_f32(f0, f1, 0, false);
    p0     = __builtin_amdgcn_cvt_pk_fp8_f32(f2, f3, p0, true);
    int p1 = __builtin_amdgcn_cvt_pk_fp8_f32(f4, f5, 0, false);
    p1     = __builtin_amdgcn_cvt_pk_fp8_f32(f6, f7, p1, true);
    uint2 w; w.x = (unsigned)p0; w.y = (unsigned)p1;
    // sliced write: slice q>>2, within-slice byte (q&3)*8
    *(uint2*)(H8 + (size_t)(q>>2)*SL_STRIDE + (size_t)row*32 + (q&3)*8) = w;
  }
}

// ---------------- sliced aggregation ----------------
// Slice s of the fp8 feature table is a CONTIGUOUS 3.2MB array -> fits one
// XCD's 4MB L2. bid = g*S + s pins slice s to XCD s (S=8) or {s,s+4} (S=4)
// under round-robin dispatch -> steady-state gathers are L2 hits.
// Block: 256 thr = 4 waves; wave w handles node g*4+w, slice s.
// Wave: 16 edge-groups x 4 lanes x uint2 (8 fp8). 16 edges/iter (pad-8 CSR,
// wave-uniform tail guard reads the zero row NN).
__global__ __launch_bounds__(256) void k_aggs(const unsigned char* __restrict__ H,
    const int* __restrict__ rp, const int* __restrict__ esrc,
    const float* __restrict__ norm, unsigned short* __restrict__ out,
    int sShift, int outStride){
  int bid = blockIdx.x;
  int sMask = (1<<sShift)-1;
  int s = bid & sMask;
  int node = ((bid >> sShift)<<2) + (threadIdx.x>>6);
  int lane = threadIdx.x & 63;
  const unsigned char* Hs = H + (size_t)s*SL_STRIDE;
  int s0 = rp[node], s1 = rp[node+1];
  int g = lane >> 2, c = lane & 3;
  f32x2 av[4] = {};
  for(int e=s0; e<s1; e+=16){
    int4 A4 = *(const int4*)(esrc+e);
    int4 B4 = *(const int4*)(esrc+e+4);
    bool more = (e+8 < s1);
    int4 C4 = more ? *(const int4*)(esrc+e+8)  : make_int4(NN,NN,NN,NN);
    int4 D4 = more ? *(const int4*)(esrc+e+12) : make_int4(NN,NN,NN,NN);
    int4 Q = (g<4)?A4 : (g<8)?B4 : (g<12)?C4 : D4;
    int sel = g & 3;
    int idx = sel==0?Q.x: sel==1?Q.y: sel==2?Q.z: Q.w;
    uint2 v = *(const uint2*)(Hs + (size_t)idx*32 + c*8);
    av[0] += __builtin_amdgcn_cvt_pk_f32_fp8((int)v.x, false);
    av[1] += __builtin_amdgcn_cvt_pk_f32_fp8((int)v.x, true );
    av[2] += __builtin_amdgcn_cvt_pk_f32_fp8((int)v.y, false);
    av[3] += __builtin_amdgcn_cvt_pk_f32_fp8((int)v.y, true );
  }
  // reduce over edge-groups (lane bits 2..5); c (bits 0..1) untouched
  #pragma unroll
  for(int off=4; off<64; off<<=1){
    #pragma unroll
    for(int j=0;j<4;j++){
      av[j][0] += __shfl_xor(av[j][0], off, 64);
      av[j][1] += __shfl_xor(av[j][1], off, 64);
    }
  }
  if(g==0){
    float nn = norm[node];
    uint4 w;
    w.x = pk2(av[0][0]*nn, av[0][1]*nn);
    w.y = pk2(av[1][0]*nn, av[1][1]*nn);
    w.z = pk2(av[2][0]*nn, av[2][1]*nn);
    w.w = pk2(av[3][0]*nn, av[3][1]*nn);
    *(uint4*)(out + (size_t)node*outStride + s*32 + c*8) = w;
  }
}

// final aggregation: X3p rows stride 64 (128B, line-aligned), cols 0-39 valid.
__global__ __launch_bounds__(64) void k_agg64(const unsigned short* __restrict__ X3p,
    const int* __restrict__ rp, const int* __restrict__ esrc,
    const float* __restrict__ norm, const float* __restrict__ b3,
    float* __restrict__ out){
  int node = blockIdx.x, lane = threadIdx.x;
  int s0 = rp[node], s1 = rp[node+1];
  int es = lane >> 3, s = lane & 7;
  float a[8] = {};
  for(int e=s0; e<s1; e+=8){
    int4 A4 = *(const int4*)(esrc+e);
    int4 B4 = *(const int4*)(esrc+e+4);
    int idx = es==0?A4.x: es==1?A4.y: es==2?A4.z: es==3?A4.w:
              es==4?B4.x: es==5?B4.y: es==6?B4.z: B4.w;
    if(s<5){
      uint4 v = *(const uint4*)(X3p + (size_t)idx*64 + s*8);
      a[0]+=bflo(v.x); a[1]+=bfhi(v.x); a[2]+=bflo(v.y); a[3]+=bfhi(v.y);
      a[4]+=bflo(v.z); a[5]+=bfhi(v.z); a[6]+=bflo(v.w); a[7]+=bfhi(v.w);
    }
  }
  #pragma unroll
  for(int off=8; off<64; off<<=1){
    #pragma unroll
    for(int j=0;j<8;j++) a[j] += __shfl_xor(a[j], off, 64);
  }
  bool act = s < 5;   // cols s*8..s*8+7 < 40
  float nn = norm[node];
  float bv[8] = {};
  if(act){
    float4 t0 = *(const float4*)(b3 + s*8);
    float4 t1 = *(const float4*)(b3 + s*8 + 4);
    bv[0]=t0.x; bv[1]=t0.y; bv[2]=t0.z; bv[3]=t0.w;
    bv[4]=t1.x; bv[5]=t1.y; bv[6]=t1.z; bv[7]=t1.w;
  }
  float v[8];
  float mx = -INFINITY;
  #pragma unroll
  for(int j=0;j<8;j++){
    v[j] = act ? (a[j]*nn + bv[j]) : -INFINITY;
    mx = fmaxf(mx, v[j]);
  }
  #pragma unroll
  for(int off=32; off; off>>=1) mx = fmaxf(mx, __shfl_xor(mx, off, 64));
  float sum = 0.f;
  if(act && es==0){
    #pragma unroll
    for(int j=0;j<8;j++) sum += expf(v[j]-mx);
  }
  #pragma unroll
  for(int off=32; off; off>>=1) sum += __shfl_xor(sum, off, 64);
  float lse = logf(sum);
  if(act && es==0){
    float4 o0, o1;
    o0.x=v[0]-mx-lse; o0.y=v[1]-mx-lse; o0.z=v[2]-mx-lse; o0.w=v[3]-mx-lse;
    o1.x=v[4]-mx-lse; o1.y=v[5]-mx-lse; o1.z=v[6]-mx-lse; o1.w=v[7]-mx-lse;
    *(float4*)(out + (size_t)node*40 + s*8) = o0;
    *(float4*)(out + (size_t)node*40 + s*8 + 4) = o1;
  }
}

// ---------------- MFMA GEMM: C = A*Bt^T + bias (bf16 out) + fused column stats ----------------

__global__ __launch_bounds__(256) void k_mgemm(
    const unsigned short* __restrict__ A, const unsigned short* __restrict__ Bt,
    const float* __restrict__ bias, unsigned short* __restrict__ C,
    float* __restrict__ sums, int M, int K, int Nn){
  __shared__ unsigned short As[128*64];
  __shared__ unsigned short Bs[128*64];
  int nt = Nn >> 7;
  int bm = blockIdx.x / nt, bn = blockIdx.x % nt;
  int m0 = bm*128, n0 = bn*128;
  int tid = threadIdx.x;
  int wave = tid >> 6, lane = tid & 63;
  int wm = (wave>>1)*64, wn = (wave&1)*64;
  int lrow = lane & 15, lq = lane >> 4;
  int srow = lane >> 3;
  int sx = ((lane & 7) ^ srow) * 8;
  f32x4 acc[4][4] = {};
  for(int k0=0; k0<K; k0+=64){
    __syncthreads();
    #pragma unroll
    for(int c4=0;c4<4;c4++){
      int c = wave*4 + c4;
      int grow = c*8 + srow;
      const unsigned short* ga = A + (size_t)(m0+grow)*K + k0 + sx;
      __builtin_amdgcn_global_load_lds((const __attribute__((address_space(1))) void*)ga,
          (__attribute__((address_space(3))) void*)(As + (size_t)c*512), 16, 0, 0);
      const unsigned short* gb = Bt + (size_t)(n0+grow)*K + k0 + sx;
      __builtin_amdgcn_global_load_lds((const __attribute__((address_space(1))) void*)gb,
          (__attribute__((address_space(3))) void*)(Bs + (size_t)c*512), 16, 0, 0);
    }
    __syncthreads();
    #pragma unroll
    for(int kk=0;kk<2;kk++){
      short8 af[4], bf[4];
      #pragma unroll
      for(int i=0;i<4;i++){
        int Ra = wm + i*16 + lrow;
        int ca = (kk*4 + lq) ^ (Ra & 7);
        af[i] = *(const short8*)(As + Ra*64 + ca*8);
        int Rb = wn + i*16 + lrow;
        int cb = (kk*4 + lq) ^ (Rb & 7);
        bf[i] = *(const short8*)(Bs + Rb*64 + cb*8);
      }
      #pragma unroll
      for(int i=0;i<4;i++)
        #pragma unroll
        for(int j=0;j<4;j++)
          acc[i][j] = __builtin_amdgcn_mfma_f32_16x16x32_bf16(af[i], bf[j], acc[i][j], 0, 0, 0);
    }
  }
  // epilogue: write C (bf16) and accumulate column sum/sumsq for BN stats
  #pragma unroll
  for(int j=0;j<4;j++){
    int col = n0 + wn + j*16 + lrow;
    float bj = bias[col];
    float s=0.f, s2=0.f;
    #pragma unroll
    for(int i=0;i<4;i++){
      #pragma unroll
      for(int r=0;r<4;r++){
        int row = m0 + wm + i*16 + lq*4 + r;
        if(row < M){
          float v = acc[i][j][r] + bj;
          s += v; s2 += v*v;
          C[(size_t)row*Nn + col] = f2bf(v);
        }
      }
    }
    s  += __shfl_xor(s, 16, 64);  s  += __shfl_xor(s, 32, 64);
    s2 += __shfl_xor(s2, 16, 64); s2 += __shfl_xor(s2, 32, 64);
    if(lq == 0){
      atomicAdd(&sums[col], s);
      atomicAdd(&sums[256+col], s2);
    }
  }
}

// layer-3: 128x64 tile; BN finalize computed per-block in LDS; A-staging applies
// BN+ReLU on the fly (reg->LDS); out X3p bf16 stride 64 (*rownorm), cols<40.
__global__ __launch_bounds__(256) void k_mgemm3(
    const unsigned short* __restrict__ Zin, const unsigned short* __restrict__ Bt,
    const float* __restrict__ sums, const float* __restrict__ gamma,
    const float* __restrict__ beta, const float* __restrict__ rownorm,
    unsigned short* __restrict__ X3p, int M, int K){
  __shared__ unsigned short As[128*64];
  __shared__ unsigned short Bs[64*64];
  __shared__ float s_sc[256], s_sh[256];
  int m0 = blockIdx.x*128;
  int tid = threadIdx.x;
  {
    float mean = sums[tid]*(1.0f/NN);
    float var  = sums[256+tid]*(1.0f/NN) - mean*mean;
    float sc = gamma[tid]*rsqrtf(var + BN_EPS);
    s_sc[tid] = sc;
    s_sh[tid] = beta[tid] - mean*sc;
  }
  __syncthreads();
  int wave = tid >> 6, lane = tid & 63;
  int wm = wave*32;
  int lrow = lane & 15, lq = lane >> 4;
  int srow = lane >> 3;
  int sx = ((lane & 7) ^ srow) * 8;
  f32x4 acc[2][4] = {};
  for(int k0=0; k0<K; k0+=64){
    // prefetch raw A (pre-BN Z2) to regs while previous iter computes
    uint4 raw[4];
    #pragma unroll
    for(int c4=0;c4<4;c4++){
      int c = wave*4 + c4;
      int grow = c*8 + srow;
      raw[c4] = *(const uint4*)(Zin + (size_t)(m0+grow)*K + k0 + sx);
    }
    float4 sc0 = *(const float4*)(s_sc + k0 + sx);
    float4 sc1 = *(const float4*)(s_sc + k0 + sx + 4);
    float4 sh0 = *(const float4*)(s_sh + k0 + sx);
    float4 sh1 = *(const float4*)(s_sh + k0 + sx + 4);
    __syncthreads();                 // previous iter's LDS reads done
    #pragma unroll
    for(int c4=0;c4<4;c4++){
      int c = wave*4 + c4;
      uint4 w;
      w.x = pk2(fmaxf(bflo(raw[c4].x)*sc0.x+sh0.x,0.f), fmaxf(bfhi(raw[c4].x)*sc0.y+sh0.y,0.f));
      w.y = pk2(fmaxf(bflo(raw[c4].y)*sc0.z+sh0.z,0.f), fmaxf(bfhi(raw[c4].y)*sc0.w+sh0.w,0.f));
      w.z = pk2(fmaxf(bflo(raw[c4].z)*sc1.x+sh1.x,0.f), fmaxf(bfhi(raw[c4].z)*sc1.y+sh1.y,0.f));
      w.w = pk2(fmaxf(bflo(raw[c4].w)*sc1.z+sh1.z,0.f), fmaxf(bfhi(raw[c4].w)*sc1.w+sh1.w,0.f));
      *(uint4*)(As + (size_t)c*512 + (size_t)lane*8) = w;
    }
    #pragma unroll
    for(int c4=0;c4<2;c4++){
      int c = wave*2 + c4;
      int grow = c*8 + srow;            // 0..63
      const unsigned short* gb = Bt + (size_t)grow*K + k0 + sx;
      __builtin_amdgcn_global_load_lds((const __attribute__((address_space(1))) void*)gb,
          (__attribute__((address_space(3))) void*)(Bs + (size_t)c*512), 16, 0, 0);
    }
    __syncthreads();
    #pragma unroll
    for(int kk=0;kk<2;kk++){
      short8 af[2], bf[4];
      #pragma unroll
      for(int i=0;i<2;i++){
        int Ra = wm + i*16 + lrow;
        int ca = (kk*4 + lq) ^ (Ra & 7);
        af[i] = *(const short8*)(As + Ra*64 + ca*8);
      }
      #pragma unroll
      for(int j=0;j<4;j++){
        int Rb = j*16 + lrow;
        int cb = (kk*4 + lq) ^ (Rb & 7);
        bf[j] = *(const short8*)(Bs + Rb*64 + cb*8);
      }
      #pragma unroll
      for(int i=0;i<2;i++)
        #pragma unroll
        for(int j=0;j<4;j++)
          acc[i][j] = __builtin_amdgcn_mfma_f32_16x16x32_bf16(af[i], bf[j], acc[i][j], 0, 0, 0);
    }
  }
  #pragma unroll
  for(int j=0;j<4;j++){
    int col = j*16 + lrow;
    if(col < 40){
      #pragma unroll
      for(int i=0;i<2;i++){
        #pragma unroll
        for(int r=0;r<4;r++){
          int row = m0 + wm + i*16 + lq*4 + r;
          if(row < M) X3p[(size_t)row*64 + col] = f2bf(acc[i][j][r] * rownorm[row]);
        }
      }
    }
  }
}

// ---------------- launch ----------------

extern "C" void kernel_launch(void* const* d_in, const int* in_sizes, int n_in,
                              void* d_out, int out_size, void* d_ws, size_t ws_size,
                              hipStream_t stream){
  const float* x   = (const float*)d_in[0];
  const int*   src = (const int*)d_in[1];
  const int*   dst = (const int*)d_in[2];
  const float* W1  = (const float*)d_in[3];
  const float* b1  = (const float*)d_in[4];
  const float* g1  = (const float*)d_in[5];
  const float* be1 = (const float*)d_in[6];
  const float* W2  = (const float*)d_in[7];
  const float* b2  = (const float*)d_in[8];
  const float* g2  = (const float*)d_in[9];
  const float* be2 = (const float*)d_in[10];
  const float* W3  = (const float*)d_in[11];
  const float* b3  = (const float*)d_in[12];
  float* out = (float*)d_out;
  const int N = NN;
  const int E = in_sizes[1];

  char* p = (char*)d_ws;
  size_t off = 0;
  auto alloc = [&](size_t bytes)->void*{
    void* r = p + off;
    off += (bytes + 511) & ~(size_t)511;
    return r;
  };
  // Footprint ~171 MB — under the ~229 MB known-good high-water mark.
  int*   bcnt  = (int*)  alloc((size_t)NBUCK*16*4);  // line-padded bucket counters
  float* sums1 = (float*)alloc(2048);
  float* sums2 = (float*)alloc(2048);
  size_t zero_bytes = off;                           // bcnt|sums zeroed each call
  int*   rp    = (int*)  alloc((size_t)(N+1)*4);
  float* norm  = (float*)alloc((size_t)(N+1)*4);
  int*   deg   = (int*)  alloc((size_t)N*4);
  int*   ptot  = (int*)  alloc((size_t)NBUCK*4);
  int*   bbase = (int*)  alloc((size_t)(NBUCK+1)*4);
  unsigned short* Wt1 = (unsigned short*)alloc((size_t)256*128*2);
  unsigned short* Wt2 = (unsigned short*)alloc((size_t)256*256*2);
  unsigned short* Wt3 = (unsigned short*)alloc((size_t)64*256*2);
  int*   esrc  = (int*)  alloc((size_t)(E + 7*N + 16)*4);            // pad-8 CSR
  unsigned short* Hx  = (unsigned short*)alloc((size_t)(N+1)*128*2); // fp8 slice region
  unsigned short* M1  = (unsigned short*)alloc((size_t)N*128*2);     // agg out (bf16)
  unsigned short* Mb2 = (unsigned short*)alloc((size_t)N*256*2);     // agg out
  unsigned short* Z   = (unsigned short*)alloc((size_t)(N+1)*256*2); // mgemm out + zero row
  unsigned short* X3p = (unsigned short*)alloc((size_t)(N+1)*64*2);  // layer-3 proj (64-col stride)
  // epairs (packed bucket words, 782*6400*4 = 20MB) aliases Mb2 (51.2MB):
  // dead before k_aggs writes Mb2 on this single stream.
  int* epairs = (int*)Mb2;
  // Hx8 = 4 slice arrays x 3.2MB = 12.8MB; H8 = 8 slice arrays x 3.2MB = 25.6MB.
  // Both live in the Hx region (25.6MB); H8 written AFTER layer-1 consumed Hx8.
  unsigned char* Hx8 = (unsigned char*)Hx;
  unsigned char* H8  = (unsigned char*)Hx;
  (void)ws_size; (void)n_in; (void)out_size;

  hipMemsetAsync(d_ws, 0, zero_bytes, stream);

  k_b1    <<<(E+T1_TILE-1)/T1_TILE,256,0,stream>>>(src, dst, bcnt, epairs, E);
  k_b2a   <<<NBUCK,256,0,stream>>>(epairs, bcnt, norm, deg, ptot);
  k_scanB <<<1,1024,0,stream>>>(ptot, bbase, rp, norm);
  k_b2b   <<<NBUCK,256,0,stream>>>(epairs, bcnt, bbase, deg, rp, esrc);
  k_prep  <<<PB_END,256,0,stream>>>(W1, W2, W3, x, norm, Wt1, Wt2, Wt3, Hx8, X3p, Z);

  // layer 1: sliced fp8 gather (S=4, slice L2-resident in 2 XCDs) -> MFMA -> Z1
  k_aggs  <<<(N/4)*4,256,0,stream>>>(Hx8, rp, esrc, norm, M1, 2, 128);
  k_mgemm <<<((N+127)/128)*2,256,0,stream>>>(M1, Wt1, b1, Z, sums1, N, 128, 256);

  // layer 2: H8 sliced fp8 (BN finalize inline) -> sliced gather (S=8, slice
  // L2-resident per XCD) -> MFMA -> Z2
  k_bnrelu8<<<((N+1)*32+255)/256,256,0,stream>>>(Z, sums1, g1, be1, norm, H8, (N+1)*32);
  k_aggs  <<<(N/4)*8,256,0,stream>>>(H8, rp, esrc, norm, Mb2, 3, 256);
  k_mgemm <<<((N+127)/128)*2,256,0,stream>>>(Mb2, Wt2, b2, Z, sums2, N, 256, 256);

  // layer 3: mgemm3 (BN finalize inline) applies BN+ReLU to Z2 in staging,
  // X3p = (relu(bn(Z2))@W3p)*norm, stride 64; then agg64 + bias + log_softmax
  k_mgemm3 <<<(N+127)/128,256,0,stream>>>(Z, Wt3, sums2, g2, be2, norm, X3p, N, 256);
  k_agg64  <<<N,64,0,stream>>>(X3p, rp, esrc, norm, b3, out);
}

// Round 11
// 677.415 us; speedup vs baseline: 1.5147x; 1.5147x over previous
//
#include <hip/hip_runtime.h>
#include <cstdint>
#include <cstddef>

#define NN 100000
#define BN_EPS 1e-5f

// bucketed CSR build: 128 nodes per bucket
#define NB_SHIFT 7
#define NBUCK ((NN >> NB_SHIFT) + 1)   // 782
#define BSLOT 6400                     // pair slots per bucket (mean 4093, sigma 64)
#define T1_EPT 16
#define T1_TILE (256*T1_EPT)           // 4096 edges per pass-1 block

typedef __attribute__((ext_vector_type(8))) short short8;
typedef __attribute__((ext_vector_type(4))) float f32x4;
typedef __attribute__((ext_vector_type(2))) float f32x2;
typedef __attribute__((ext_vector_type(4))) int i32x4;
typedef __attribute__((ext_vector_type(4))) unsigned u32x4;
typedef __attribute__((ext_vector_type(2))) unsigned u32x2;

static __device__ __forceinline__ float bflo(unsigned u){ return __uint_as_float(u<<16); }
static __device__ __forceinline__ float bfhi(unsigned u){ return __uint_as_float(u & 0xFFFF0000u); }
static __device__ __forceinline__ unsigned short f2bf(float f){
  unsigned u = __float_as_uint(f);
  u += 0x7FFFu + ((u>>16)&1u);   // round-to-nearest-even
  return (unsigned short)(u>>16);
}
static __device__ __forceinline__ unsigned pk2(float a, float b){
  return (unsigned)f2bf(a) | ((unsigned)f2bf(b) << 16);
}
// non-temporal stream helpers: keep one-pass streams out of L2/L3 so the
// randomly-gathered fp8 tables stay resident (round-10 counter anomaly:
// 25.6MB L3-fit table refetched 330MB/launch -> eviction by own write stream)
static __device__ __forceinline__ i32x4 ldnt(const int* p){
  return __builtin_nontemporal_load((const i32x4*)p);
}

// ---------------- graph prep (bucketed, histogram-free CSR build) ----------------

// pass 1: partition edges into NBUCK fixed-capacity segments of packed
// (src | localdst<<20) words. src < 2^17, localdst = dst&127 in bits 20..26.
__global__ __launch_bounds__(256) void k_b1(const int* __restrict__ src,
    const int* __restrict__ dst, int* __restrict__ bcnt,
    int* __restrict__ epairs, int E){
  __shared__ int hist[NBUCK];
  int tid = threadIdx.x;
  for(int j=tid; j<NBUCK; j+=256) hist[j]=0;
  __syncthreads();
  int base = blockIdx.x*T1_TILE;
  int pk[T1_EPT], bk[T1_EPT], r[T1_EPT];
  #pragma unroll
  for(int i=0;i<T1_EPT;i++){
    int e = base + i*256 + tid;
    if(e<E){
      int s=src[e], d=dst[e];
      bk[i]=d>>NB_SHIFT;
      pk[i]= s | ((d&127)<<20);
      r[i]=atomicAdd(&hist[bk[i]], 1);
    }
  }
  __syncthreads();
  for(int j=tid; j<NBUCK; j+=256){
    int h = hist[j];
    if(h>0) hist[j] = atomicAdd(&bcnt[j*16], h);   // replace count with segment base
  }
  __syncthreads();
  #pragma unroll
  for(int i=0;i<T1_EPT;i++){
    int e = base + i*256 + tid;
    if(e<E) epairs[(size_t)bk[i]*BSLOT + hist[bk[i]] + r[i]] = pk[i];
  }
}

// pass 2a: per-bucket LDS degree histogram -> norm[], deg[], padded bucket total.
__global__ __launch_bounds__(256) void k_b2a(const int* __restrict__ epairs,
    const int* __restrict__ bcnt, float* __restrict__ norm, int* __restrict__ deg,
    int* __restrict__ ptot){
  __shared__ int h[128];
  int b = blockIdx.x, tid = threadIdx.x;
  if(tid<128) h[tid]=0;
  __syncthreads();
  int c = bcnt[b*16];
  const int* ep = epairs + (size_t)b*BSLOT;
  for(int j=tid; j<c; j+=256) atomicAdd(&h[ep[j]>>20], 1);
  __syncthreads();
  int n0 = b<<NB_SHIFT, nmax = min(128, NN-n0);
  if(tid<nmax){
    norm[n0+tid] = rsqrtf(fmaxf((float)h[tid], 1.0f));
    deg[n0+tid] = h[tid];
  }
  if(tid<64){
    int p0=(h[2*tid]+7)&~7, p1=(h[2*tid+1]+7)&~7;
    int s=p0+p1;
    #pragma unroll
    for(int off=1; off<64; off<<=1) s += __shfl_xor(s, off, 64);
    if(tid==0) ptot[b]=s;
  }
}

// scan over 782 bucket totals (tiny); also rp[NN] and norm[NN]=0.
__global__ __launch_bounds__(1024) void k_scanB(const int* __restrict__ ptot,
    int* __restrict__ bbase, int* __restrict__ rp, float* __restrict__ norm){
  __shared__ int sm[1024];
  int t = threadIdx.x;
  int v = (t<NBUCK)? ptot[t] : 0;
  sm[t]=v; __syncthreads();
  for(int off=1; off<1024; off<<=1){
    int u = (t>=off)? sm[t-off] : 0;
    __syncthreads();
    sm[t]+=u;
    __syncthreads();
  }
  if(t<NBUCK) bbase[t] = sm[t]-v;
  if(t==NBUCK-1){ bbase[NBUCK]=sm[t]; rp[NN]=sm[t]; }
  if(t==0) norm[NN]=0.f;
}

// pass 2b: load deg, wave shuffle-scan of padded counts -> rp, place edges via
// LDS atomics, write pad slots (NN).
__global__ __launch_bounds__(256) void k_b2b(const int* __restrict__ epairs,
    const int* __restrict__ bcnt, const int* __restrict__ bbase,
    const int* __restrict__ deg, int* __restrict__ rp, int* __restrict__ esrc){
  __shared__ int h[128];
  __shared__ int loc[129];
  int b = blockIdx.x, tid = threadIdx.x;
  int n0 = b<<NB_SHIFT, nmax = min(128, NN-n0);
  if(tid<128) h[tid] = (tid<nmax) ? deg[n0+tid] : 0;
  __syncthreads();
  if(tid<64){
    int p0=(h[2*tid]+7)&~7, p1=(h[2*tid+1]+7)&~7;
    int s=p0+p1;
    #pragma unroll
    for(int off=1; off<64; off<<=1){ int u=__shfl_up(s, off, 64); if(tid>=off) s+=u; }
    loc[2*tid]   = s-p0-p1;
    loc[2*tid+1] = s-p1;
    if(tid==63) loc[128]=s;
  }
  __syncthreads();
  int base = bbase[b];
  if(tid<nmax) rp[n0+tid] = base + loc[tid];
  if(tid<128) h[tid] = base + loc[tid];          // becomes fill pointer
  __syncthreads();
  int c = bcnt[b*16];
  const int* ep = epairs + (size_t)b*BSLOT;
  for(int j=tid; j<c; j+=256){
    int p = ep[j];
    int pos = atomicAdd(&h[p>>20], 1);
    esrc[pos] = p & 0xFFFFF;
  }
  __syncthreads();
  for(int i=tid; i<nmax; i+=256){
    int end = base + loc[i+1];
    for(int j=h[i]; j<end; j++) esrc[j]=NN;
  }
}

// ---------------- fused prep: zeropad + 3x wprep + scale_x(fp8) ----------------
// bid 0: zero pad rows. bids [1,129): W1 transp. [129,385): W2 transp.
// [385,449): W3 pack. [449,6699): Hx8 = fp8(x*norm), 8 elems/thread.
#define PB_W1 1
#define PB_W2 129
#define PB_W3 385
#define PB_SX 449
#define PB_END (PB_SX + 6250)

__global__ __launch_bounds__(256) void k_prep(
    const float* __restrict__ W1, const float* __restrict__ W2, const float* __restrict__ W3,
    const float* __restrict__ x, const float* __restrict__ norm,
    unsigned short* __restrict__ Wt1, unsigned short* __restrict__ Wt2,
    unsigned short* __restrict__ Wt3, unsigned char* __restrict__ Hx8,
    unsigned short* __restrict__ X3p, unsigned short* __restrict__ Z){
  int bid = blockIdx.x, t = threadIdx.x;
  if(bid == 0){
    if(t<128) Hx8[(size_t)NN*128 + t] = 0;
    if(t<40)  X3p[(size_t)NN*64 + t] = 0;
    Z[(size_t)NN*256 + t] = 0;
  }else if(bid < PB_W2){
    int i = (bid-PB_W1)*256 + t;          // < 128*256
    int k = i >> 8, n = i & 255;
    Wt1[(size_t)n*128 + k] = f2bf(W1[i]);
  }else if(bid < PB_W3){
    int i = (bid-PB_W2)*256 + t;          // < 256*256
    int k = i >> 8, n = i & 255;
    Wt2[(size_t)n*256 + k] = f2bf(W2[i]);
  }else if(bid < PB_SX){
    int i = (bid-PB_W3)*256 + t;          // < 64*256
    int n = i >> 8, k = i & 255;
    Wt3[i] = (n < 40) ? f2bf(W3[(size_t)k*40 + n]) : (unsigned short)0;
  }else{
    int i = (bid-PB_SX)*256 + t;          // < N*16 (8 elems each)
    f32x4 v0 = __builtin_nontemporal_load((const f32x4*)(x + (size_t)i*8));
    f32x4 v1 = __builtin_nontemporal_load((const f32x4*)(x + (size_t)i*8 + 4));
    float nn = norm[i>>4];                // 16 threads per 128-col row
    int p0 = __builtin_amdgcn_cvt_pk_fp8_f32(v0.x*nn, v0.y*nn, 0, false);
    p0     = __builtin_amdgcn_cvt_pk_fp8_f32(v0.z*nn, v0.w*nn, p0, true);
    int p1 = __builtin_amdgcn_cvt_pk_fp8_f32(v1.x*nn, v1.y*nn, 0, false);
    p1     = __builtin_amdgcn_cvt_pk_fp8_f32(v1.z*nn, v1.w*nn, p1, true);
    uint2 w; w.x = (unsigned)p0; w.y = (unsigned)p1;
    *(uint2*)(Hx8 + (size_t)i*8) = w;     // table: cached store
  }
}

// ---------------- BN+ReLU pass -> fp8 e4m3 (BN finalize folded in) ----------------

// H8 = fp8(relu(bn(Z1)) * norm[row]), over N+1 rows (row NN -> 0 via norm=0).
// Z read is a one-pass stream (NT); H8 is the gather table (cached stores).
__global__ __launch_bounds__(256) void k_bnrelu8(const unsigned short* __restrict__ Z,
    const float* __restrict__ sums, const float* __restrict__ gamma,
    const float* __restrict__ beta, const float* __restrict__ norm,
    unsigned char* __restrict__ H8, int total4){
  __shared__ float s_sc[256], s_sh[256];
  int t = threadIdx.x;
  {
    float mean = sums[t]*(1.0f/NN);
    float var  = sums[256+t]*(1.0f/NN) - mean*mean;
    float sc = gamma[t]*rsqrtf(var + BN_EPS);
    s_sc[t] = sc;
    s_sh[t] = beta[t] - mean*sc;
  }
  __syncthreads();
  int i = blockIdx.x*blockDim.x + t;
  if(i<total4){
    int c8 = (i & 31) * 8;
    float nn = norm[i>>5];
    u32x4 v = __builtin_nontemporal_load((const u32x4*)(Z + (size_t)i*8));
    float4 sc0 = *(const float4*)(s_sc + c8);
    float4 sc1 = *(const float4*)(s_sc + c8 + 4);
    float4 sh0 = *(const float4*)(s_sh + c8);
    float4 sh1 = *(const float4*)(s_sh + c8 + 4);
    float f0 = fmaxf(bflo(v.x)*sc0.x+sh0.x,0.f)*nn;
    float f1 = fmaxf(bfhi(v.x)*sc0.y+sh0.y,0.f)*nn;
    float f2 = fmaxf(bflo(v.y)*sc0.z+sh0.z,0.f)*nn;
    float f3 = fmaxf(bfhi(v.y)*sc0.w+sh0.w,0.f)*nn;
    float f4 = fmaxf(bflo(v.z)*sc1.x+sh1.x,0.f)*nn;
    float f5 = fmaxf(bfhi(v.z)*sc1.y+sh1.y,0.f)*nn;
    float f6 = fmaxf(bflo(v.w)*sc1.z+sh1.z,0.f)*nn;
    float f7 = fmaxf(bfhi(v.w)*sc1.w+sh1.w,0.f)*nn;
    int p0 = __builtin_amdgcn_cvt_pk_fp8_f32(f0, f1, 0, false);
    p0     = __builtin_amdgcn_cvt_pk_fp8_f32(f2, f3, p0, true);
    int p1 = __builtin_amdgcn_cvt_pk_fp8_f32(f4, f5, 0, false);
    p1     = __builtin_amdgcn_cvt_pk_fp8_f32(f6, f7, p1, true);
    uint2 w; w.x = (unsigned)p0; w.y = (unsigned)p1;
    *(uint2*)(H8 + (size_t)i*8) = w;      // table: cached store
  }
}

// ---------------- aggregation (padded CSR, fp8 gathers, NT streams) ----------------
// Gather loads CACHED (tables are L3-fit); esrc loads + output stores NT so the
// streams don't evict the tables.

// 128-col fp8 rows (128B = one line, no col split). 8 edge-groups x 8 lanes x
// uint4 (16 fp8). f32x2 accumulators -> v_pk_add_f32.
__global__ __launch_bounds__(64) void k_agg128f8(const unsigned char* __restrict__ H,
    const int* __restrict__ rp, const int* __restrict__ esrc,
    const float* __restrict__ norm, unsigned short* __restrict__ out){
  int node = blockIdx.x, lane = threadIdx.x;
  int s0 = rp[node], s1 = rp[node+1];
  int g = lane >> 3, c = lane & 7;
  f32x2 av[8] = {};
  for(int e=s0; e<s1; e+=8){
    i32x4 A4 = ldnt(esrc+e);
    i32x4 B4 = ldnt(esrc+e+4);
    int idx = g<4 ? (g==0?A4.x: g==1?A4.y: g==2?A4.z: A4.w)
                  : (g==4?B4.x: g==5?B4.y: g==6?B4.z: B4.w);
    uint4 v = *(const uint4*)(H + (size_t)idx*128 + c*16);
    av[0] += __builtin_amdgcn_cvt_pk_f32_fp8((int)v.x, false);
    av[1] += __builtin_amdgcn_cvt_pk_f32_fp8((int)v.x, true );
    av[2] += __builtin_amdgcn_cvt_pk_f32_fp8((int)v.y, false);
    av[3] += __builtin_amdgcn_cvt_pk_f32_fp8((int)v.y, true );
    av[4] += __builtin_amdgcn_cvt_pk_f32_fp8((int)v.z, false);
    av[5] += __builtin_amdgcn_cvt_pk_f32_fp8((int)v.z, true );
    av[6] += __builtin_amdgcn_cvt_pk_f32_fp8((int)v.w, false);
    av[7] += __builtin_amdgcn_cvt_pk_f32_fp8((int)v.w, true );
  }
  #pragma unroll
  for(int off=8; off<64; off<<=1){
    #pragma unroll
    for(int j=0;j<8;j++){
      av[j][0] += __shfl_xor(av[j][0], off, 64);
      av[j][1] += __shfl_xor(av[j][1], off, 64);
    }
  }
  if(g==0){
    float nn = norm[node];
    u32x4 w0, w1;
    w0.x = pk2(av[0][0]*nn, av[0][1]*nn); w0.y = pk2(av[1][0]*nn, av[1][1]*nn);
    w0.z = pk2(av[2][0]*nn, av[2][1]*nn); w0.w = pk2(av[3][0]*nn, av[3][1]*nn);
    w1.x = pk2(av[4][0]*nn, av[4][1]*nn); w1.y = pk2(av[5][0]*nn, av[5][1]*nn);
    w1.z = pk2(av[6][0]*nn, av[6][1]*nn); w1.w = pk2(av[7][0]*nn, av[7][1]*nn);
    unsigned short* o = out + (size_t)node*128 + c*16;
    __builtin_nontemporal_store(w0, (u32x4*)o);
    __builtin_nontemporal_store(w1, (u32x4*)(o+8));
  }
}

// 256-col fp8 rows (256B): 2 halves x 128 cols (128B fp8, XCD-parity split).
// 8 edge-groups x 8 lanes x uint4 (16 fp8). f32x2 accumulators.
__global__ __launch_bounds__(64) void k_agg256h(const unsigned char* __restrict__ H,
    const int* __restrict__ rp, const int* __restrict__ esrc,
    const float* __restrict__ norm, unsigned short* __restrict__ out){
  int bid = blockIdx.x;
  int half = bid & 1, node = bid >> 1;
  int lane = threadIdx.x;
  int s0 = rp[node], s1 = rp[node+1];
  int g = lane >> 3, c = lane & 7;
  const unsigned char* Hh = H + half*128;
  f32x2 av[8] = {};
  for(int e=s0; e<s1; e+=8){
    i32x4 A4 = ldnt(esrc+e);
    i32x4 B4 = ldnt(esrc+e+4);
    int idx = g<4 ? (g==0?A4.x: g==1?A4.y: g==2?A4.z: A4.w)
                  : (g==4?B4.x: g==5?B4.y: g==6?B4.z: B4.w);
    uint4 v = *(const uint4*)(Hh + (size_t)idx*256 + c*16);
    av[0] += __builtin_amdgcn_cvt_pk_f32_fp8((int)v.x, false);
    av[1] += __builtin_amdgcn_cvt_pk_f32_fp8((int)v.x, true );
    av[2] += __builtin_amdgcn_cvt_pk_f32_fp8((int)v.y, false);
    av[3] += __builtin_amdgcn_cvt_pk_f32_fp8((int)v.y, true );
    av[4] += __builtin_amdgcn_cvt_pk_f32_fp8((int)v.z, false);
    av[5] += __builtin_amdgcn_cvt_pk_f32_fp8((int)v.z, true );
    av[6] += __builtin_amdgcn_cvt_pk_f32_fp8((int)v.w, false);
    av[7] += __builtin_amdgcn_cvt_pk_f32_fp8((int)v.w, true );
  }
  #pragma unroll
  for(int off=8; off<64; off<<=1){
    #pragma unroll
    for(int j=0;j<8;j++){
      av[j][0] += __shfl_xor(av[j][0], off, 64);
      av[j][1] += __shfl_xor(av[j][1], off, 64);
    }
  }
  if(g==0){
    float nn = norm[node];
    u32x4 w0, w1;
    w0.x = pk2(av[0][0]*nn, av[0][1]*nn); w0.y = pk2(av[1][0]*nn, av[1][1]*nn);
    w0.z = pk2(av[2][0]*nn, av[2][1]*nn); w0.w = pk2(av[3][0]*nn, av[3][1]*nn);
    w1.x = pk2(av[4][0]*nn, av[4][1]*nn); w1.y = pk2(av[5][0]*nn, av[5][1]*nn);
    w1.z = pk2(av[6][0]*nn, av[6][1]*nn); w1.w = pk2(av[7][0]*nn, av[7][1]*nn);
    unsigned short* o = out + (size_t)node*256 + half*128 + c*16;
    __builtin_nontemporal_store(w0, (u32x4*)o);
    __builtin_nontemporal_store(w1, (u32x4*)(o+8));
  }
}

// final aggregation: X3p rows stride 64 (128B, line-aligned), cols 0-39 valid.
__global__ __launch_bounds__(64) void k_agg64(const unsigned short* __restrict__ X3p,
    const int* __restrict__ rp, const int* __restrict__ esrc,
    const float* __restrict__ norm, const float* __restrict__ b3,
    float* __restrict__ out){
  int node = blockIdx.x, lane = threadIdx.x;
  int s0 = rp[node], s1 = rp[node+1];
  int es = lane >> 3, s = lane & 7;
  float a[8] = {};
  for(int e=s0; e<s1; e+=8){
    i32x4 A4 = ldnt(esrc+e);
    i32x4 B4 = ldnt(esrc+e+4);
    int idx = es==0?A4.x: es==1?A4.y: es==2?A4.z: es==3?A4.w:
              es==4?B4.x: es==5?B4.y: es==6?B4.z: B4.w;
    if(s<5){
      uint4 v = *(const uint4*)(X3p + (size_t)idx*64 + s*8);
      a[0]+=bflo(v.x); a[1]+=bfhi(v.x); a[2]+=bflo(v.y); a[3]+=bfhi(v.y);
      a[4]+=bflo(v.z); a[5]+=bfhi(v.z); a[6]+=bflo(v.w); a[7]+=bfhi(v.w);
    }
  }
  #pragma unroll
  for(int off=8; off<64; off<<=1){
    #pragma unroll
    for(int j=0;j<8;j++) a[j] += __shfl_xor(a[j], off, 64);
  }
  bool act = s < 5;   // cols s*8..s*8+7 < 40
  float nn = norm[node];
  float bv[8] = {};
  if(act){
    float4 t0 = *(const float4*)(b3 + s*8);
    float4 t1 = *(const float4*)(b3 + s*8 + 4);
    bv[0]=t0.x; bv[1]=t0.y; bv[2]=t0.z; bv[3]=t0.w;
    bv[4]=t1.x; bv[5]=t1.y; bv[6]=t1.z; bv[7]=t1.w;
  }
  float v[8];
  float mx = -INFINITY;
  #pragma unroll
  for(int j=0;j<8;j++){
    v[j] = act ? (a[j]*nn + bv[j]) : -INFINITY;
    mx = fmaxf(mx, v[j]);
  }
  #pragma unroll
  for(int off=32; off; off>>=1) mx = fmaxf(mx, __shfl_xor(mx, off, 64));
  float sum = 0.f;
  if(act && es==0){
    #pragma unroll
    for(int j=0;j<8;j++) sum += expf(v[j]-mx);
  }
  #pragma unroll
  for(int off=32; off; off>>=1) sum += __shfl_xor(sum, off, 64);
  float lse = logf(sum);
  if(act && es==0){
    f32x4 o0, o1;
    o0.x=v[0]-mx-lse; o0.y=v[1]-mx-lse; o0.z=v[2]-mx-lse; o0.w=v[3]-mx-lse;
    o1.x=v[4]-mx-lse; o1.y=v[5]-mx-lse; o1.z=v[6]-mx-lse; o1.w=v[7]-mx-lse;
    __builtin_nontemporal_store(o0, (f32x4*)(out + (size_t)node*40 + s*8));
    __builtin_nontemporal_store(o1, (f32x4*)(out + (size_t)node*40 + s*8 + 4));
  }
}

// ---------------- MFMA GEMM: C = A*Bt^T + bias (bf16 out) + fused column stats ----------------

__global__ __launch_bounds__(256) void k_mgemm(
    const unsigned short* __restrict__ A, const unsigned short* __restrict__ Bt,
    const float* __restrict__ bias, unsigned short* __restrict__ C,
    float* __restrict__ sums, int M, int K, int Nn){
  __shared__ unsigned short As[128*64];
  __shared__ unsigned short Bs[128*64];
  int nt = Nn >> 7;
  int bm = blockIdx.x / nt, bn = blockIdx.x % nt;
  int m0 = bm*128, n0 = bn*128;
  int tid = threadIdx.x;
  int wave = tid >> 6, lane = tid & 63;
  int wm = (wave>>1)*64, wn = (wave&1)*64;
  int lrow = lane & 15, lq = lane >> 4;
  int srow = lane >> 3;
  int sx = ((lane & 7) ^ srow) * 8;
  f32x4 acc[4][4] = {};
  for(int k0=0; k0<K; k0+=64){
    __syncthreads();
    #pragma unroll
    for(int c4=0;c4<4;c4++){
      int c = wave*4 + c4;
      int grow = c*8 + srow;
      const unsigned short* ga = A + (size_t)(m0+grow)*K + k0 + sx;
      __builtin_amdgcn_global_load_lds((const __attribute__((address_space(1))) void*)ga,
          (__attribute__((address_space(3))) void*)(As + (size_t)c*512), 16, 0, 0);
      const unsigned short* gb = Bt + (size_t)(n0+grow)*K + k0 + sx;
      __builtin_amdgcn_global_load_lds((const __attribute__((address_space(1))) void*)gb,
          (__attribute__((address_space(3))) void*)(Bs + (size_t)c*512), 16, 0, 0);
    }
    __syncthreads();
    #pragma unroll
    for(int kk=0;kk<2;kk++){
      short8 af[4], bf[4];
      #pragma unroll
      for(int i=0;i<4;i++){
        int Ra = wm + i*16 + lrow;
        int ca = (kk*4 + lq) ^ (Ra & 7);
        af[i] = *(const short8*)(As + Ra*64 + ca*8);
        int Rb = wn + i*16 + lrow;
        int cb = (kk*4 + lq) ^ (Rb & 7);
        bf[i] = *(const short8*)(Bs + Rb*64 + cb*8);
      }
      #pragma unroll
      for(int i=0;i<4;i++)
        #pragma unroll
        for(int j=0;j<4;j++)
          acc[i][j] = __builtin_amdgcn_mfma_f32_16x16x32_bf16(af[i], bf[j], acc[i][j], 0, 0, 0);
    }
  }
  // epilogue: write C (bf16) and accumulate column sum/sumsq for BN stats
  #pragma unroll
  for(int j=0;j<4;j++){
    int col = n0 + wn + j*16 + lrow;
    float bj = bias[col];
    float s=0.f, s2=0.f;
    #pragma unroll
    for(int i=0;i<4;i++){
      #pragma unroll
      for(int r=0;r<4;r++){
        int row = m0 + wm + i*16 + lq*4 + r;
        if(row < M){
          float v = acc[i][j][r] + bj;
          s += v; s2 += v*v;
          C[(size_t)row*Nn + col] = f2bf(v);
        }
      }
    }
    s  += __shfl_xor(s, 16, 64);  s  += __shfl_xor(s, 32, 64);
    s2 += __shfl_xor(s2, 16, 64); s2 += __shfl_xor(s2, 32, 64);
    if(lq == 0){
      atomicAdd(&sums[col], s);
      atomicAdd(&sums[256+col], s2);
    }
  }
}

// layer-3: 128x64 tile; BN finalize computed per-block in LDS; A-staging applies
// BN+ReLU on the fly (reg->LDS); out X3p bf16 stride 64 (*rownorm), cols<40.
__global__ __launch_bounds__(256) void k_mgemm3(
    const unsigned short* __restrict__ Zin, const unsigned short* __restrict__ Bt,
    const float* __restrict__ sums, const float* __restrict__ gamma,
    const float* __restrict__ beta, const float* __restrict__ rownorm,
    unsigned short* __restrict__ X3p, int M, int K){
  __shared__ unsigned short As[128*64];
  __shared__ unsigned short Bs[64*64];
  __shared__ float s_sc[256], s_sh[256];
  int m0 = blockIdx.x*128;
  int tid = threadIdx.x;
  {
    float mean = sums[tid]*(1.0f/NN);
    float var  = sums[256+tid]*(1.0f/NN) - mean*mean;
    float sc = gamma[tid]*rsqrtf(var + BN_EPS);
    s_sc[tid] = sc;
    s_sh[tid] = beta[tid] - mean*sc;
  }
  __syncthreads();
  int wave = tid >> 6, lane = tid & 63;
  int wm = wave*32;
  int lrow = lane & 15, lq = lane >> 4;
  int srow = lane >> 3;
  int sx = ((lane & 7) ^ srow) * 8;
  f32x4 acc[2][4] = {};
  for(int k0=0; k0<K; k0+=64){
    // prefetch raw A (pre-BN Z2) to regs while previous iter computes
    uint4 raw[4];
    #pragma unroll
    for(int c4=0;c4<4;c4++){
      int c = wave*4 + c4;
      int grow = c*8 + srow;
      raw[c4] = *(const uint4*)(Zin + (size_t)(m0+grow)*K + k0 + sx);
    }
    float4 sc0 = *(const float4*)(s_sc + k0 + sx);
    float4 sc1 = *(const float4*)(s_sc + k0 + sx + 4);
    float4 sh0 = *(const float4*)(s_sh + k0 + sx);
    float4 sh1 = *(const float4*)(s_sh + k0 + sx + 4);
    __syncthreads();                 // previous iter's LDS reads done
    #pragma unroll
    for(int c4=0;c4<4;c4++){
      int c = wave*4 + c4;
      uint4 w;
      w.x = pk2(fmaxf(bflo(raw[c4].x)*sc0.x+sh0.x,0.f), fmaxf(bfhi(raw[c4].x)*sc0.y+sh0.y,0.f));
      w.y = pk2(fmaxf(bflo(raw[c4].y)*sc0.z+sh0.z,0.f), fmaxf(bfhi(raw[c4].y)*sc0.w+sh0.w,0.f));
      w.z = pk2(fmaxf(bflo(raw[c4].z)*sc1.x+sh1.x,0.f), fmaxf(bfhi(raw[c4].z)*sc1.y+sh1.y,0.f));
      w.w = pk2(fmaxf(bflo(raw[c4].w)*sc1.z+sh1.z,0.f), fmaxf(bfhi(raw[c4].w)*sc1.w+sh1.w,0.f));
      *(uint4*)(As + (size_t)c*512 + (size_t)lane*8) = w;
    }
    #pragma unroll
    for(int c4=0;c4<2;c4++){
      int c = wave*2 + c4;
      int grow = c*8 + srow;            // 0..63
      const unsigned short* gb = Bt + (size_t)grow*K + k0 + sx;
      __builtin_amdgcn_global_load_lds((const __attribute__((address_space(1))) void*)gb,
          (__attribute__((address_space(3))) void*)(Bs + (size_t)c*512), 16, 0, 0);
    }
    __syncthreads();
    #pragma unroll
    for(int kk=0;kk<2;kk++){
      short8 af[2], bf[4];
      #pragma unroll
      for(int i=0;i<2;i++){
        int Ra = wm + i*16 + lrow;
        int ca = (kk*4 + lq) ^ (Ra & 7);
        af[i] = *(const short8*)(As + Ra*64 + ca*8);
      }
      #pragma unroll
      for(int j=0;j<4;j++){
        int Rb = j*16 + lrow;
        int cb = (kk*4 + lq) ^ (Rb & 7);
        bf[j] = *(const short8*)(Bs + Rb*64 + cb*8);
      }
      #pragma unroll
      for(int i=0;i<2;i++)
        #pragma unroll
        for(int j=0;j<4;j++)
          acc[i][j] = __builtin_amdgcn_mfma_f32_16x16x32_bf16(af[i], bf[j], acc[i][j], 0, 0, 0);
    }
  }
  #pragma unroll
  for(int j=0;j<4;j++){
    int col = j*16 + lrow;
    if(col < 40){
      #pragma unroll
      for(int i=0;i<2;i++){
        #pragma unroll
        for(int r=0;r<4;r++){
          int row = m0 + wm + i*16 + lq*4 + r;
          if(row < M) X3p[(size_t)row*64 + col] = f2bf(acc[i][j][r] * rownorm[row]);
        }
      }
    }
  }
}

// ---------------- launch ----------------

extern "C" void kernel_launch(void* const* d_in, const int* in_sizes, int n_in,
                              void* d_out, int out_size, void* d_ws, size_t ws_size,
                              hipStream_t stream){
  const float* x   = (const float*)d_in[0];
  const int*   src = (const int*)d_in[1];
  const int*   dst = (const int*)d_in[2];
  const float* W1  = (const float*)d_in[3];
  const float* b1  = (const float*)d_in[4];
  const float* g1  = (const float*)d_in[5];
  const float* be1 = (const float*)d_in[6];
  const float* W2  = (const float*)d_in[7];
  const float* b2  = (const float*)d_in[8];
  const float* g2  = (const float*)d_in[9];
  const float* be2 = (const float*)d_in[10];
  const float* W3  = (const float*)d_in[11];
  const float* b3  = (const float*)d_in[12];
  float* out = (float*)d_out;
  const int N = NN;
  const int E = in_sizes[1];

  char* p = (char*)d_ws;
  size_t off = 0;
  auto alloc = [&](size_t bytes)->void*{
    void* r = p + off;
    off += (bytes + 511) & ~(size_t)511;
    return r;
  };
  // Footprint ~184 MB — under the ~229 MB known-good high-water mark.
  int*   bcnt  = (int*)  alloc((size_t)NBUCK*16*4);  // line-padded bucket counters
  float* sums1 = (float*)alloc(2048);
  float* sums2 = (float*)alloc(2048);
  size_t zero_bytes = off;                           // bcnt|sums zeroed each call
  int*   rp    = (int*)  alloc((size_t)(N+1)*4);
  float* norm  = (float*)alloc((size_t)(N+1)*4);
  int*   deg   = (int*)  alloc((size_t)N*4);
  int*   ptot  = (int*)  alloc((size_t)NBUCK*4);
  int*   bbase = (int*)  alloc((size_t)(NBUCK+1)*4);
  unsigned short* Wt1 = (unsigned short*)alloc((size_t)256*128*2);
  unsigned short* Wt2 = (unsigned short*)alloc((size_t)256*256*2);
  unsigned short* Wt3 = (unsigned short*)alloc((size_t)64*256*2);
  int*   esrc  = (int*)  alloc((size_t)(E + 7*N + 16)*4);            // pad-8 CSR
  unsigned short* Hx  = (unsigned short*)alloc((size_t)(N+1)*128*2); // fp8 region (see below)
  unsigned short* M1  = (unsigned short*)alloc((size_t)N*128*2);     // agg128 out (bf16)
  unsigned short* Mb2 = (unsigned short*)alloc((size_t)N*256*2);     // agg256 out
  unsigned short* Z   = (unsigned short*)alloc((size_t)(N+1)*256*2); // mgemm out + zero row
  unsigned short* X3p = (unsigned short*)alloc((size_t)(N+1)*64*2);  // layer-3 proj (64-col stride)
  // epairs (packed bucket words, 782*6400*4 = 20MB) aliases Mb2 (51.2MB):
  // dead before k_agg256h writes Mb2 on this single stream.
  int* epairs = (int*)Mb2;
  // Hx8 = fp8(x*norm), (N+1)x128x1B = 12.8MB in the Hx region (25.6MB).
  // H8 = fp8(relu(bn(Z1))*norm), (N+1)x256x1B = 25.6MB, same region —
  // written by k_bnrelu8 AFTER agg128f8/mgemm consumed Hx8 (stream-ordered).
  unsigned char* Hx8 = (unsigned char*)Hx;
  unsigned char* H8  = (unsigned char*)Hx;
  (void)ws_size; (void)n_in; (void)out_size;

  hipMemsetAsync(d_ws, 0, zero_bytes, stream);

  k_b1    <<<(E+T1_TILE-1)/T1_TILE,256,0,stream>>>(src, dst, bcnt, epairs, E);
  k_b2a   <<<NBUCK,256,0,stream>>>(epairs, bcnt, norm, deg, ptot);
  k_scanB <<<1,1024,0,stream>>>(ptot, bbase, rp, norm);
  k_b2b   <<<NBUCK,256,0,stream>>>(epairs, bcnt, bbase, deg, rp, esrc);
  k_prep  <<<PB_END,256,0,stream>>>(W1, W2, W3, x, norm, Wt1, Wt2, Wt3, Hx8, X3p, Z);

  // layer 1: agg128f8 (fp8 gather, NT streams) -> MFMA @W1+b1 (+stats) -> Z1(bf16)
  k_agg128f8<<<N,64,0,stream>>>(Hx8, rp, esrc, norm, M1);
  k_mgemm  <<<((N+127)/128)*2,256,0,stream>>>(M1, Wt1, b1, Z, sums1, N, 128, 256);

  // layer 2: H8 = fp8(relu(bn(Z1))*norm) -> agg256h (fp8 gather, NT streams) -> MFMA -> Z2
  k_bnrelu8<<<((N+1)*32+255)/256,256,0,stream>>>(Z, sums1, g1, be1, norm, H8, (N+1)*32);
  k_agg256h<<<2*N,64,0,stream>>>(H8, rp, esrc, norm, Mb2);
  k_mgemm  <<<((N+127)/128)*2,256,0,stream>>>(Mb2, Wt2, b2, Z, sums2, N, 256, 256);

  // layer 3: mgemm3 (BN finalize inline) applies BN+ReLU to Z2 in staging,
  // X3p = (relu(bn(Z2))@W3p)*norm, stride 64; then agg64 + bias + log_softmax
  k_mgemm3 <<<(N+127)/128,256,0,stream>>>(Z, Wt3, sums2, g2, be2, norm, X3p, N, 256);
  k_agg64  <<<N,64,0,stream>>>(X3p, rp, esrc, norm, b3, out);
}